// Round 4
// baseline (201.270 us; speedup 1.0000x reference)
//
#include <hip/hip_runtime.h>
#include <hip/hip_bf16.h>

#define B_ 256
#define S_ 256
#define T_ 128
#define START_ 126
#define STOP_ 127

typedef __attribute__((ext_vector_type(8))) short short8;
typedef __attribute__((ext_vector_type(4))) float f32x4;
typedef __attribute__((ext_vector_type(4))) int i32x4;

// float -> bf16 bits, round-to-nearest-even
__device__ __forceinline__ unsigned short f2bf(float f) {
    unsigned u = __float_as_uint(f);
    return (unsigned short)((u + 0x7FFFu + ((u >> 16) & 1u)) >> 16);
}

// One wave per sequence. Zero-shuffle recurrence:
//   A = et^T (constant, in registers), B = ep broadcast over N-columns.
//   With the shared A/B k-map mu(g, e=2q+h) = (2kt+h)*16 + 4g + q, the
//   D-fragment of step t (acc[rt][q] = u[16rt+4g+q]) is EXACTLY the data
//   each lane needs for step t+1's B-fragment: state hand-off is pure VALU
//   (16 cvt_pk + 32 muls), no LDS/bpermute on the critical path.
__global__ __launch_bounds__(64, 1) void crf_fwd(
    const float* __restrict__ feats,      // [B, S, T]
    const float* __restrict__ trans,      // [T, T]
    const int*   __restrict__ tags,       // [B, S]
    const int*   __restrict__ mask,       // [B, S]
    float* __restrict__ out)              // [1]
{
    const int b = blockIdx.x;
    const int l = threadIdx.x;            // 0..63
    const int g = l >> 4;
    const int c = l & 15;
    const float* fb = feats + (size_t)b * (S_ * T_);

    __shared__ float efb[2][8][T_];       // exp(feat) rows, dbuf chunks of 8

    // ---- A fragments: et^T with the mu k-map, held in registers ----
    short8 afrag[4][8];                   // [kt][rt]
    #pragma unroll
    for (int kt = 0; kt < 4; ++kt) {
        #pragma unroll
        for (int rt = 0; rt < 8; ++rt) {
            short8 f;
            #pragma unroll
            for (int e = 0; e < 8; ++e) {
                const int k = (2 * kt + (e & 1)) * 16 + 4 * g + (e >> 1);
                f[e] = (short)f2bf(__expf(trans[k * T_ + rt * 16 + c]));
            }
            afrag[kt][rt] = f;
        }
    }

    // ---- sequence length (prefix mask) ----
    int cnt = 0;
    #pragma unroll
    for (int s4 = 0; s4 < 4; ++s4) cnt += mask[b * S_ + s4 * 64 + l];
    #pragma unroll
    for (int o = 32; o; o >>= 1) cnt += __shfl_xor(cnt, o, 64);
    const int len = cnt;                  // >= 128

    // ---- stage chunk 0 (rows 0..7) of exp(feat) into LDS ----
    {
        const int row = l >> 3, cb = (l & 7) * 16;
        #pragma unroll
        for (int i = 0; i < 4; ++i) {
            float4 v = *(const float4*)&fb[row * T_ + cb + 4 * i];
            float4 e;
            e.x = __expf(v.x); e.y = __expf(v.y);
            e.z = __expf(v.z); e.w = __expf(v.w);
            *(float4*)&efb[0][row][cb + 4 * i] = e;
        }
    }
    asm volatile("s_waitcnt lgkmcnt(0)" ::: "memory");

    // ---- init state t=0: held[rt][q] = exp(feat0[j] + trans[START][j]) ----
    float held[8][4];
    #pragma unroll
    for (int rt = 0; rt < 8; ++rt) {
        #pragma unroll
        for (int q = 0; q < 4; ++q) {
            const int j = rt * 16 + 4 * g + q;
            held[rt][q] = __expf(fb[j] + trans[START_ * T_ + j]);
        }
    }
    float M = 0.f;

    // state as bf16 B-fragments
    short8 bfrag[4];
    #pragma unroll
    for (int kt = 0; kt < 4; ++kt) {
        i32x4 t4;
        #pragma unroll
        for (int q = 0; q < 4; ++q) {
            unsigned r;
            asm("v_cvt_pk_bf16_f32 %0, %1, %2" : "=v"(r)
                : "v"(held[2 * kt][q]), "v"(held[2 * kt + 1][q]));
            t4[q] = (int)r;
        }
        bfrag[kt] = *(short8*)&t4;
    }

    // ---- main recurrence ----
    float4 pre4[4];
    int pend = 0;
    for (int t = 1; t < S_; ++t) {
        if (t >= len) break;
        const int bc = (t >> 3) & 1, tr = t & 7;

        // issue next-chunk global loads early (consumed ~5 steps later)
        if (tr == 1) {
            const int nb = (t >> 3) + 1;
            if (nb < S_ / 8) {
                const int row = l >> 3, cb = (l & 7) * 16;
                #pragma unroll
                for (int i = 0; i < 4; ++i)
                    pre4[i] = *(const float4*)&fb[(nb * 8 + row) * T_ + cb + 4 * i];
                pend = 1;
            }
        }

        // ef for this step: 8 broadcast b128 reads (off the dep chain)
        float4 ef4[8];
        #pragma unroll
        for (int rt = 0; rt < 8; ++rt)
            ef4[rt] = *(const float4*)&efb[bc][tr][rt * 16 + 4 * g];

        // 32 MFMAs: 8 independent chains (rt), kt-serial within chain
        f32x4 acc[8];
        #pragma unroll
        for (int rt = 0; rt < 8; ++rt) acc[rt] = (f32x4){0.f, 0.f, 0.f, 0.f};
        #pragma unroll
        for (int kt = 0; kt < 4; ++kt) {
            #pragma unroll
            for (int rt = 0; rt < 8; ++rt)
                acc[rt] = __builtin_amdgcn_mfma_f32_16x16x32_bf16(
                    afrag[kt][rt], bfrag[kt], acc[rt], 0, 0, 0);
        }

        // write prefetched chunk to the other LDS buffer (off dep chain)
        if (tr == 6 && pend) {
            const int dst = ((t >> 3) + 1) & 1;
            const int row = l >> 3, cb = (l & 7) * 16;
            #pragma unroll
            for (int i = 0; i < 4; ++i) {
                float4 e;
                e.x = __expf(pre4[i].x); e.y = __expf(pre4[i].y);
                e.z = __expf(pre4[i].z); e.w = __expf(pre4[i].w);
                *(float4*)&efb[dst][row][cb + 4 * i] = e;
            }
            pend = 0;
            asm volatile("s_waitcnt lgkmcnt(0)" ::: "memory");
        }

        // u = D * exp(feat_t)
        #pragma unroll
        for (int rt = 0; rt < 8; ++rt) {
            held[rt][0] = acc[rt][0] * ef4[rt].x;
            held[rt][1] = acc[rt][1] * ef4[rt].y;
            held[rt][2] = acc[rt][2] * ef4[rt].z;
            held[rt][3] = acc[rt][3] * ef4[rt].w;
        }

        // renorm every 4 steps by a wave-uniform representative scale
        if ((t & 3) == 0) {
            const float sc = __uint_as_float(
                __builtin_amdgcn_readfirstlane(__float_as_uint(held[0][0])));
            const float rs = 1.0f / sc;
            #pragma unroll
            for (int rt = 0; rt < 8; ++rt) {
                #pragma unroll
                for (int q = 0; q < 4; ++q) held[rt][q] *= rs;
            }
            M += __logf(sc);
        }

        // repack state into B-fragments (pure VALU)
        #pragma unroll
        for (int kt = 0; kt < 4; ++kt) {
            i32x4 t4;
            #pragma unroll
            for (int q = 0; q < 4; ++q) {
                unsigned r;
                asm("v_cvt_pk_bf16_f32 %0, %1, %2" : "=v"(r)
                    : "v"(held[2 * kt][q]), "v"(held[2 * kt + 1][q]));
                t4[q] = (int)r;
            }
            bfrag[kt] = *(short8*)&t4;
        }
    }

    // ---- forward score: M + log(sum_j held[j] * exp(trans[j][STOP])) ----
    float v = 0.f;
    #pragma unroll
    for (int rt = 0; rt < 8; ++rt) {
        #pragma unroll
        for (int q = 0; q < 4; ++q) {
            const int j = rt * 16 + 4 * g + q;
            v += held[rt][q] * __expf(trans[j * T_ + STOP_]);
        }
    }
    v += __shfl_xor(v, 16, 64);   // combine g ^ 1
    v += __shfl_xor(v, 32, 64);   // combine g ^ 2
    const float fwd = M + __logf(v);

    // ---- gold path score ----
    float gg = 0.f;
    #pragma unroll
    for (int s4 = 0; s4 < 4; ++s4) {
        const int s = s4 * 64 + l;
        if (mask[b * S_ + s]) {
            const int tg = tags[b * S_ + s];
            const int pv = (s == 0) ? START_ : tags[b * S_ + s - 1];
            gg += fb[s * T_ + tg] + trans[pv * T_ + tg];
            if (s == len - 1) gg += trans[tg * T_ + STOP_];
        }
    }
    #pragma unroll
    for (int o = 32; o; o >>= 1) gg += __shfl_xor(gg, o, 64);

    if (l == 0) atomicAdd(out, fwd - gg);
}

extern "C" void kernel_launch(void* const* d_in, const int* in_sizes, int n_in,
                              void* d_out, int out_size, void* d_ws, size_t ws_size,
                              hipStream_t stream) {
    const float* feats = (const float*)d_in[0];
    const float* trans = (const float*)d_in[1];
    const int*   tags  = (const int*)d_in[2];
    const int*   mask  = (const int*)d_in[3];
    float* out = (float*)d_out;

    hipMemsetAsync(out, 0, sizeof(float), stream);
    crf_fwd<<<dim3(B_), dim3(64), 0, stream>>>(feats, trans, tags, mask, out);
}

// Round 5
// 194.766 us; speedup vs baseline: 1.0334x; 1.0334x over previous
//
#include <hip/hip_runtime.h>
#include <hip/hip_bf16.h>

#define B_ 256
#define S_ 256
#define T_ 128
#define START_ 126
#define STOP_ 127

typedef __attribute__((ext_vector_type(8))) short short8;
typedef __attribute__((ext_vector_type(4))) float f32x4;
typedef __attribute__((ext_vector_type(4))) int i32x4;

// float -> bf16 bits, round-to-nearest-even
__device__ __forceinline__ unsigned short f2bf(float f) {
    unsigned u = __float_as_uint(f);
    return (unsigned short)((u + 0x7FFFu + ((u >> 16) & 1u)) >> 16);
}

// MFMA with A-operand read DIRECTLY from AGPRs (ISA supports A/B from AGPR;
// the intrinsic forces VGPR class and caused a v_accvgpr_read copy storm).
// First MFMA of each chain uses inline-constant 0 as C (no acc zero-init).
#define MFMA_INIT(accv, af, bf) \
    asm("v_mfma_f32_16x16x32_bf16 %0, %1, %2, 0" \
        : "=v"(accv) : "a"(af), "v"(bf))
#define MFMA_ACC(accv, af, bf) \
    asm("v_mfma_f32_16x16x32_bf16 %0, %1, %2, %0" \
        : "+v"(accv) : "a"(af), "v"(bf))

// One wave per sequence. Zero-shuffle recurrence:
//   A = et^T (constant, in AGPRs), B = ep broadcast over N-columns.
//   Shared A/B k-map mu(g, e=2q+h) = (2kt+h)*16 + 4g + q makes step t's
//   D-fragment (acc[rt][q] = u[16rt+4g+q]) exactly step t+1's B-fragment
//   data: state hand-off is pure VALU (16 cvt_pk + 32 muls).
__global__ __launch_bounds__(64, 1) void crf_fwd(
    const float* __restrict__ feats,      // [B, S, T]
    const float* __restrict__ trans,      // [T, T]
    const int*   __restrict__ tags,       // [B, S]
    const int*   __restrict__ mask,       // [B, S]
    float* __restrict__ out)              // [1]
{
    const int b = blockIdx.x;
    const int l = threadIdx.x;            // 0..63
    const int g = l >> 4;
    const int c = l & 15;
    const float* fb = feats + (size_t)b * (S_ * T_);

    __shared__ float efb[2][8][T_];       // exp(feat) rows, dbuf chunks of 8

    // ---- A fragments: et^T with the mu k-map (homed in AGPRs by the asm) ----
    short8 afrag[4][8];                   // [kt][rt]
    #pragma unroll
    for (int kt = 0; kt < 4; ++kt) {
        #pragma unroll
        for (int rt = 0; rt < 8; ++rt) {
            short8 f;
            #pragma unroll
            for (int e = 0; e < 8; ++e) {
                const int k = (2 * kt + (e & 1)) * 16 + 4 * g + (e >> 1);
                f[e] = (short)f2bf(__expf(trans[k * T_ + rt * 16 + c]));
            }
            afrag[kt][rt] = f;
        }
    }

    // ---- sequence length (prefix mask) ----
    int cnt = 0;
    #pragma unroll
    for (int s4 = 0; s4 < 4; ++s4) cnt += mask[b * S_ + s4 * 64 + l];
    #pragma unroll
    for (int o = 32; o; o >>= 1) cnt += __shfl_xor(cnt, o, 64);
    const int len = cnt;                  // >= 128

    // ---- stage chunk 0 (rows 0..7) of exp(feat) into LDS ----
    {
        const int row = l >> 3, cb = (l & 7) * 16;
        #pragma unroll
        for (int i = 0; i < 4; ++i) {
            float4 v = *(const float4*)&fb[row * T_ + cb + 4 * i];
            float4 e;
            e.x = __expf(v.x); e.y = __expf(v.y);
            e.z = __expf(v.z); e.w = __expf(v.w);
            *(float4*)&efb[0][row][cb + 4 * i] = e;
        }
    }
    asm volatile("s_waitcnt lgkmcnt(0)" ::: "memory");

    // ---- init state t=0: held[rt][q] = exp(feat0[j] + trans[START][j]) ----
    float held[8][4];
    #pragma unroll
    for (int rt = 0; rt < 8; ++rt) {
        #pragma unroll
        for (int q = 0; q < 4; ++q) {
            const int j = rt * 16 + 4 * g + q;
            held[rt][q] = __expf(fb[j] + trans[START_ * T_ + j]);
        }
    }
    float M = 0.f;

    // state as bf16 B-fragments
    short8 bfrag[4];
    #pragma unroll
    for (int kt = 0; kt < 4; ++kt) {
        i32x4 t4;
        #pragma unroll
        for (int q = 0; q < 4; ++q) {
            unsigned r;
            asm("v_cvt_pk_bf16_f32 %0, %1, %2" : "=v"(r)
                : "v"(held[2 * kt][q]), "v"(held[2 * kt + 1][q]));
            t4[q] = (int)r;
        }
        bfrag[kt] = *(short8*)&t4;
    }

    // ---- main recurrence ----
    float4 pre4[4];
    int pend = 0;
    for (int t = 1; t < S_; ++t) {
        if (t >= len) break;
        const int bc = (t >> 3) & 1, tr = t & 7;

        // issue next-chunk global loads early (consumed ~5 steps later)
        if (tr == 1) {
            const int nb = (t >> 3) + 1;
            if (nb < S_ / 8) {
                const int row = l >> 3, cb = (l & 7) * 16;
                #pragma unroll
                for (int i = 0; i < 4; ++i)
                    pre4[i] = *(const float4*)&fb[(nb * 8 + row) * T_ + cb + 4 * i];
                pend = 1;
            }
        }

        // ef for this step: 8 broadcast b128 reads (off the dep chain)
        float4 ef4[8];
        #pragma unroll
        for (int rt = 0; rt < 8; ++rt)
            ef4[rt] = *(const float4*)&efb[bc][tr][rt * 16 + 4 * g];

        // 32 MFMAs: 8 independent chains (rt), kt-serial within chain.
        // A read straight from AGPRs; C of first MFMA is inline 0.
        f32x4 acc[8];
        #pragma unroll
        for (int rt = 0; rt < 8; ++rt) MFMA_INIT(acc[rt], afrag[0][rt], bfrag[0]);
        #pragma unroll
        for (int kt = 1; kt < 4; ++kt) {
            #pragma unroll
            for (int rt = 0; rt < 8; ++rt)
                MFMA_ACC(acc[rt], afrag[kt][rt], bfrag[kt]);
        }

        // write prefetched chunk to the other LDS buffer (off dep chain)
        if (tr == 6 && pend) {
            const int dst = ((t >> 3) + 1) & 1;
            const int row = l >> 3, cb = (l & 7) * 16;
            #pragma unroll
            for (int i = 0; i < 4; ++i) {
                float4 e;
                e.x = __expf(pre4[i].x); e.y = __expf(pre4[i].y);
                e.z = __expf(pre4[i].z); e.w = __expf(pre4[i].w);
                *(float4*)&efb[dst][row][cb + 4 * i] = e;
            }
            pend = 0;
            asm volatile("s_waitcnt lgkmcnt(0)" ::: "memory");
        }

        // u = D * exp(feat_t)
        #pragma unroll
        for (int rt = 0; rt < 8; ++rt) {
            held[rt][0] = acc[rt][0] * ef4[rt].x;
            held[rt][1] = acc[rt][1] * ef4[rt].y;
            held[rt][2] = acc[rt][2] * ef4[rt].z;
            held[rt][3] = acc[rt][3] * ef4[rt].w;
        }

        // renorm every 4 steps by a wave-uniform representative scale
        if ((t & 3) == 0) {
            const float sc = __uint_as_float(
                __builtin_amdgcn_readfirstlane(__float_as_uint(held[0][0])));
            const float rs = __builtin_amdgcn_rcpf(sc);
            #pragma unroll
            for (int rt = 0; rt < 8; ++rt) {
                #pragma unroll
                for (int q = 0; q < 4; ++q) held[rt][q] *= rs;
            }
            M += __logf(sc);
        }

        // repack state into B-fragments (pure VALU)
        #pragma unroll
        for (int kt = 0; kt < 4; ++kt) {
            i32x4 t4;
            #pragma unroll
            for (int q = 0; q < 4; ++q) {
                unsigned r;
                asm("v_cvt_pk_bf16_f32 %0, %1, %2" : "=v"(r)
                    : "v"(held[2 * kt][q]), "v"(held[2 * kt + 1][q]));
                t4[q] = (int)r;
            }
            bfrag[kt] = *(short8*)&t4;
        }
    }

    // ---- forward score: M + log(sum_j held[j] * exp(trans[j][STOP])) ----
    float v = 0.f;
    #pragma unroll
    for (int rt = 0; rt < 8; ++rt) {
        #pragma unroll
        for (int q = 0; q < 4; ++q) {
            const int j = rt * 16 + 4 * g + q;
            v += held[rt][q] * __expf(trans[j * T_ + STOP_]);
        }
    }
    v += __shfl_xor(v, 16, 64);   // combine g ^ 1
    v += __shfl_xor(v, 32, 64);   // combine g ^ 2
    const float fwd = M + __logf(v);

    // ---- gold path score ----
    float gg = 0.f;
    #pragma unroll
    for (int s4 = 0; s4 < 4; ++s4) {
        const int s = s4 * 64 + l;
        if (mask[b * S_ + s]) {
            const int tg = tags[b * S_ + s];
            const int pv = (s == 0) ? START_ : tags[b * S_ + s - 1];
            gg += fb[s * T_ + tg] + trans[pv * T_ + tg];
            if (s == len - 1) gg += trans[tg * T_ + STOP_];
        }
    }
    #pragma unroll
    for (int o = 32; o; o >>= 1) gg += __shfl_xor(gg, o, 64);

    if (l == 0) atomicAdd(out, fwd - gg);
}

extern "C" void kernel_launch(void* const* d_in, const int* in_sizes, int n_in,
                              void* d_out, int out_size, void* d_ws, size_t ws_size,
                              hipStream_t stream) {
    const float* feats = (const float*)d_in[0];
    const float* trans = (const float*)d_in[1];
    const int*   tags  = (const int*)d_in[2];
    const int*   mask  = (const int*)d_in[3];
    float* out = (float*)d_out;

    hipMemsetAsync(out, 0, sizeof(float), stream);
    crf_fwd<<<dim3(B_), dim3(64), 0, stream>>>(feats, trans, tags, mask, out);
}